// Round 3
// baseline (105.070 us; speedup 1.0000x reference)
//
#include <hip/hip_runtime.h>

#define NPTS     16384
#define G        20
#define G2       400
#define ORIGIN   -5.0f
#define INV_CELL 2.0f
#define D2MAX    0.25f     // EPS^2 sentinel: contributes exactly 0 after sqrt
#define QPW      4
#define K4_NBLK  2048
#define K4_BLOCK 256
#define K4_WAVES (K4_NBLK * (K4_BLOCK / 64))   // 8192

// ---- ws layout (bytes) ----
#define OFF_COUNTS   0u        // u32[8192]
#define OFF_STARTS   32768u    // u32[8192] (cells 8000..8191 have count 0 -> start = N)
#define OFF_CURSORS  65536u    // u32[8192]
#define OFF_WLCNT    98304u    // u32
#define OFF_WL       98432u    // int2[12288]
#define OFF_PTS      262144u   // float4[16384], cell-sorted
#define OFF_CID      524288u   // u32[16384]
#define OFF_PART     589824u   // float[8192] per-wave partials
#define WS_REQUIRED  622592u

__global__ __launch_bounds__(256) void prep_zero_kernel(unsigned char* ws) {
  unsigned* counts = (unsigned*)(ws + OFF_COUNTS);
  const int i = blockIdx.x * 256 + threadIdx.x;   // 8192 threads
  counts[i] = 0u;
  if (i == 0) *(unsigned*)(ws + OFF_WLCNT) = 0u;
}

__global__ __launch_bounds__(256) void prep_hist_kernel(const float* __restrict__ q,
                                                        unsigned char* ws) {
  unsigned* counts  = (unsigned*)(ws + OFF_COUNTS);
  unsigned* cid_arr = (unsigned*)(ws + OFF_CID);
  const int i = blockIdx.x * 256 + threadIdx.x;   // 16384 threads
  const float x = q[3 * i + 0], y = q[3 * i + 1], z = q[3 * i + 2];
  int cx = (int)floorf((x - ORIGIN) * INV_CELL); cx = min(max(cx, 0), G - 1);
  int cy = (int)floorf((y - ORIGIN) * INV_CELL); cy = min(max(cy, 0), G - 1);
  int cz = (int)floorf((z - ORIGIN) * INV_CELL); cz = min(max(cz, 0), G - 1);
  const unsigned cid = (unsigned)((cx * G + cy) * G + cz);
  cid_arr[i] = cid;
  atomicAdd(counts + cid, 1u);
}

// Single block: prefix-sum cell counts -> starts; zero cursors; emit worklist
// of (quad start, cell | count) entries; write total entry count.
__global__ __launch_bounds__(1024) void prep_scan_kernel(unsigned char* ws) {
  unsigned* counts  = (unsigned*)(ws + OFF_COUNTS);
  unsigned* starts  = (unsigned*)(ws + OFF_STARTS);
  unsigned* cursors = (unsigned*)(ws + OFF_CURSORS);
  unsigned* wlcnt   = (unsigned*)(ws + OFF_WLCNT);
  int2*     wl      = (int2*)(ws + OFF_WL);

  __shared__ unsigned scnt[1024], sent[1024];
  const int t = threadIdx.x;
  unsigned c8[8];
  unsigned mycnt = 0, myent = 0;
#pragma unroll
  for (int i = 0; i < 8; ++i) {
    c8[i] = counts[t * 8 + i];
    mycnt += c8[i];
    myent += (c8[i] + 3u) >> 2;
  }
  scnt[t] = mycnt; sent[t] = myent;
  __syncthreads();
  for (int off = 1; off < 1024; off <<= 1) {
    unsigned a = 0, b = 0;
    if (t >= off) { a = scnt[t - off]; b = sent[t - off]; }
    __syncthreads();
    scnt[t] += a; sent[t] += b;
    __syncthreads();
  }
  unsigned run  = scnt[t] - mycnt;   // exclusive prefixes
  unsigned erun = sent[t] - myent;
#pragma unroll
  for (int i = 0; i < 8; ++i) {
    const int c = t * 8 + i;
    starts[c]  = run;
    cursors[c] = 0u;
    const unsigned n  = c8[i];
    const unsigned ne = (n + 3u) >> 2;
    for (unsigned g = 0; g < ne; ++g) {
      const unsigned rem = n - 4u * g;
      const unsigned cnt = rem < 4u ? rem : 4u;
      wl[erun + g] = make_int2((int)(run + 4u * g), (c << 3) | (int)cnt);
    }
    erun += ne;
    run  += n;
  }
  if (t == 1023) *wlcnt = sent[1023];
}

__global__ __launch_bounds__(256) void prep_scatter_kernel(const float* __restrict__ q,
                                                           unsigned char* ws) {
  const unsigned* starts  = (const unsigned*)(ws + OFF_STARTS);
  unsigned*       cursors = (unsigned*)(ws + OFF_CURSORS);
  const unsigned* cid_arr = (const unsigned*)(ws + OFF_CID);
  float4*         pts     = (float4*)(ws + OFF_PTS);
  const int i = blockIdx.x * 256 + threadIdx.x;   // 16384 threads
  const unsigned cid = cid_arr[i];
  const unsigned pos = starts[cid] + atomicAdd(cursors + cid, 1u);
  pts[pos] = make_float4(q[3 * i + 0], q[3 * i + 1], q[3 * i + 2], 0.0f);
}

// Main: one wave per worklist quad (<=4 queries of one cell). Wave-shared
// sorted top-8 per query; candidates = 9 contiguous z-column ranges (27
// cells), own column first so the threshold tightens early. Candidates read
// from L2 (pts = 256 KB). Self excluded via exact d2 == 0.
__global__ __launch_bounds__(K4_BLOCK) void knn_cells_kernel(unsigned char* ws) {
  const unsigned* starts = (const unsigned*)(ws + OFF_STARTS);
  const int2*     wl     = (const int2*)(ws + OFF_WL);
  const float4*   pts    = (const float4*)(ws + OFF_PTS);
  float*          part   = (float*)(ws + OFF_PART);
  const int wlc = (int)*(const unsigned*)(ws + OFF_WLCNT);

  const int lane = threadIdx.x & 63;
  const int gw   = blockIdx.x * (K4_BLOCK / 64) + (threadIdx.x >> 6);

  // column visit order {dx,dy}: own first, then faces, then corners.
  // packed 2-bit (d+1) codes for r=0..8
  const unsigned DXC = 10569u;  // {0,1,-1,0,0,1,1,-1,-1}
  const unsigned DYC = 34965u;  // {0,0,0,1,-1,1,-1,1,-1}

  float acc = 0.0f;

  for (int e = gw; e < wlc; e += K4_WAVES) {
    const int2 ent  = wl[e];
    const int qstart = ent.x;
    const int cell   = ent.y >> 3;
    const int cnt    = ent.y & 7;

    float qx[QPW], qy[QPW], qz[QPW];
#pragma unroll
    for (int k = 0; k < QPW; ++k) {
      if (k < cnt) {
        const float4 Q = pts[qstart + k];
        qx[k] = Q.x; qy[k] = Q.y; qz[k] = Q.z;
      } else {  // dummy query far away: never passes threshold, zero events
        qx[k] = 1.0e4f; qy[k] = 1.0e4f; qz[k] = 1.0e4f;
      }
    }

    float L[QPW][8];
#pragma unroll
    for (int k = 0; k < QPW; ++k)
#pragma unroll
      for (int s = 0; s < 8; ++s) L[k][s] = D2MAX;

    const int cx  = cell / G2;
    const int rem = cell - cx * G2;
    const int cy  = rem / G;
    const int cz  = rem - cy * G;
    const int zlo = cz > 0 ? cz - 1 : 0;
    const int zhi = cz < G - 1 ? cz + 1 : G - 1;

    for (int r = 0; r < 9; ++r) {
      const int dx = (int)((DXC >> (2 * r)) & 3u) - 1;
      const int dy = (int)((DYC >> (2 * r)) & 3u) - 1;
      const int nx = cx + dx, ny = cy + dy;
      if ((unsigned)nx >= (unsigned)G || (unsigned)ny >= (unsigned)G) continue;
      const int colbase = (nx * G + ny) * G;
      const int s0 = (int)starts[colbase + zlo];
      const int e0 = (int)starts[colbase + zhi + 1];

      for (int j = s0; j < e0; j += 64) {
        int idx = j + lane;
        const bool val = idx < e0;
        if (!val) idx = e0 - 1;
        const float4 P = pts[idx];
        float d2[QPW];
#pragma unroll
        for (int k = 0; k < QPW; ++k) {
          const float ddx = qx[k] - P.x;
          const float ddy = qy[k] - P.y;
          const float ddz = qz[k] - P.z;
          const float dd = fmaf(ddz, ddz, fmaf(ddy, ddy, ddx * ddx));
          d2[k] = val ? dd : 1.0e9f;   // self -> exactly 0, excluded below
        }
        unsigned long long m[QPW];
#pragma unroll
        for (int k = 0; k < QPW; ++k)
          m[k] = __ballot((d2[k] < L[k][7]) && (d2[k] != 0.0f));

        if (m[0] | m[1] | m[2] | m[3]) {
#pragma unroll
          for (int k = 0; k < QPW; ++k) {
            unsigned long long mk = m[k];
            while (mk) {
              const int i = __ffsll(mk) - 1;
              mk &= mk - 1;
              const float v = __shfl(d2[k], i);   // wave-uniform broadcast
              if (v < L[k][7]) {
                L[k][7] = fmaxf(L[k][6], fminf(v, L[k][7]));
                L[k][6] = fmaxf(L[k][5], fminf(v, L[k][6]));
                L[k][5] = fmaxf(L[k][4], fminf(v, L[k][5]));
                L[k][4] = fmaxf(L[k][3], fminf(v, L[k][4]));
                L[k][3] = fmaxf(L[k][2], fminf(v, L[k][3]));
                L[k][2] = fmaxf(L[k][1], fminf(v, L[k][2]));
                L[k][1] = fmaxf(L[k][0], fminf(v, L[k][1]));
                L[k][0] = fminf(L[k][0], v);
              }
            }
          }
        }
      }
    }

#pragma unroll
    for (int k = 0; k < QPW; ++k)
      if (k < cnt)
#pragma unroll
        for (int s = 0; s < 8; ++s) acc += 0.5f - sqrtf(L[k][s]);
  }

  if (lane == 0) part[gw] = acc;   // every wave slot written every call
}

__global__ __launch_bounds__(256) void final_reduce2_kernel(const unsigned char* ws,
                                                            float* __restrict__ out) {
  const float* part = (const float*)(ws + OFF_PART);
  const int tid = threadIdx.x;
  float v = 0.0f;
#pragma unroll
  for (int j = 0; j < 32; ++j) v += part[tid + 256 * j];
#pragma unroll
  for (int off = 1; off < 64; off <<= 1) v += __shfl_xor(v, off);
  __shared__ float r[4];
  if ((tid & 63) == 0) r[tid >> 6] = v;
  __syncthreads();
  if (tid == 0) out[0] = (r[0] + r[1] + r[2] + r[3]) * (1.0f / (float)NPTS);
}

// ---------------- v2 fallback (proven) if ws is too small ----------------
#define FB_TILE 2048
__global__ __launch_bounds__(512) void knn_loss_kernel(
    const float* __restrict__ q, float* __restrict__ block_sum) {
  __shared__ float4 tile[FB_TILE];
  __shared__ float  wsum[8];
  const int tid = threadIdx.x, lane = tid & 63, wave = tid >> 6;
  const int qbase = blockIdx.x * 32 + wave * 4;
  float qx[4], qy[4], qz[4], qq[4];
#pragma unroll
  for (int k = 0; k < 4; ++k) {
    const float x = q[3 * (qbase + k) + 0];
    const float y = q[3 * (qbase + k) + 1];
    const float z = q[3 * (qbase + k) + 2];
    qx[k] = x; qy[k] = y; qz[k] = z;
    qq[k] = fmaf(z, z, fmaf(y, y, x * x));
  }
  float L[4][8];
#pragma unroll
  for (int k = 0; k < 4; ++k)
#pragma unroll
    for (int s = 0; s < 8; ++s) L[k][s] = D2MAX;
  for (int t = 0; t < NPTS / FB_TILE; ++t) {
    const int tb = t * FB_TILE;
#pragma unroll
    for (int s2 = 0; s2 < FB_TILE / 512; ++s2) {
      const int p = s2 * 512 + tid, gp = tb + p;
      const float x = q[3 * gp], y = q[3 * gp + 1], z = q[3 * gp + 2];
      tile[p] = make_float4(x, y, z, fmaf(z, z, fmaf(y, y, x * x)));
    }
    __syncthreads();
#pragma unroll 2
    for (int s = 0; s < FB_TILE / 64; ++s) {
      const float4 p = tile[s * 64 + lane];
      float d2[4];
#pragma unroll
      for (int k = 0; k < 4; ++k) {
        const float dt = fmaf(qx[k], p.x, fmaf(qy[k], p.y, qz[k] * p.z));
        d2[k] = fmaf(-2.0f, dt, qq[k] + p.w);
      }
      unsigned long long m[4];
#pragma unroll
      for (int k = 0; k < 4; ++k) m[k] = __ballot(d2[k] < L[k][7]);
      if (m[0] | m[1] | m[2] | m[3]) {
        const int jb = tb + s * 64;
#pragma unroll
        for (int k = 0; k < 4; ++k) {
          unsigned long long mk = m[k];
          while (mk) {
            const int i = __ffsll(mk) - 1;
            mk &= mk - 1;
            const float v = __shfl(d2[k], i);
            if ((jb + i) != (qbase + k) && v < L[k][7]) {
              L[k][7] = fmaxf(L[k][6], fminf(v, L[k][7]));
              L[k][6] = fmaxf(L[k][5], fminf(v, L[k][6]));
              L[k][5] = fmaxf(L[k][4], fminf(v, L[k][5]));
              L[k][4] = fmaxf(L[k][3], fminf(v, L[k][4]));
              L[k][3] = fmaxf(L[k][2], fminf(v, L[k][3]));
              L[k][2] = fmaxf(L[k][1], fminf(v, L[k][2]));
              L[k][1] = fmaxf(L[k][0], fminf(v, L[k][1]));
              L[k][0] = fminf(L[k][0], v);
            }
          }
        }
      }
    }
    __syncthreads();
  }
  float acc = 0.0f;
#pragma unroll
  for (int k = 0; k < 4; ++k)
#pragma unroll
    for (int s = 0; s < 8; ++s) acc += 0.5f - sqrtf(fmaxf(L[k][s], 0.0f));
  if (lane == 0) wsum[wave] = acc;
  __syncthreads();
  if (tid == 0) {
    float s = 0.0f;
#pragma unroll
    for (int w = 0; w < 8; ++w) s += wsum[w];
    block_sum[blockIdx.x] = s;
  }
}

__global__ __launch_bounds__(256) void final_reduce_kernel(
    const float* __restrict__ bs, float* __restrict__ out) {
  const int tid = threadIdx.x;
  float v = bs[tid] + bs[tid + 256];
#pragma unroll
  for (int off = 1; off < 64; off <<= 1) v += __shfl_xor(v, off);
  __shared__ float r[4];
  if ((tid & 63) == 0) r[tid >> 6] = v;
  __syncthreads();
  if (tid == 0) out[0] = (r[0] + r[1] + r[2] + r[3]) * (1.0f / (float)NPTS);
}

extern "C" void kernel_launch(void* const* d_in, const int* in_sizes, int n_in,
                              void* d_out, int out_size, void* d_ws, size_t ws_size,
                              hipStream_t stream) {
  const float* q = (const float*)d_in[0];
  unsigned char* ws = (unsigned char*)d_ws;
  if (ws_size >= WS_REQUIRED) {
    prep_zero_kernel<<<32, 256, 0, stream>>>(ws);
    prep_hist_kernel<<<64, 256, 0, stream>>>(q, ws);
    prep_scan_kernel<<<1, 1024, 0, stream>>>(ws);
    prep_scatter_kernel<<<64, 256, 0, stream>>>(q, ws);
    knn_cells_kernel<<<K4_NBLK, K4_BLOCK, 0, stream>>>(ws);
    final_reduce2_kernel<<<1, 256, 0, stream>>>(ws, (float*)d_out);
  } else {
    float* block_sum = (float*)d_ws;
    knn_loss_kernel<<<512, 512, 0, stream>>>(q, block_sum);
    final_reduce_kernel<<<1, 256, 0, stream>>>(block_sum, (float*)d_out);
  }
}

// Round 4
// 86.834 us; speedup vs baseline: 1.2100x; 1.2100x over previous
//
#include <hip/hip_runtime.h>

#define NPTS     16384
#define G        20
#define G2       400
#define ORIGIN   -5.0f
#define INV_CELL 2.0f
#define D2MAX    0.25f     // EPS^2 sentinel: contributes exactly 0 after sqrt
#define QPW      8         // queries per worklist entry / wave

#define KNN_BLOCK 256
#define KNN_GRID  2560
#define KNN_WAVES (KNN_GRID * (KNN_BLOCK / 64))   // 10240 >= max wlcnt (10048)

// ---- ws layout (bytes) ----
#define OFF_COUNTS   0u        // u32[8192]
#define OFF_STARTS   32768u    // u32[8192]
#define OFF_CURSORS  65536u    // u32[8192]
#define OFF_WLCNT    98304u    // u32 (written by scan, no pre-zero needed)
#define OFF_WL       98432u    // int2[12288] >= worst case 8000 + 2048 entries
#define OFF_PTS      262144u   // float4[16384], cell-sorted
#define OFF_CID      524288u   // u32[16384]
#define OFF_PART     589824u   // float[10048] per-entry partials
#define WS_REQUIRED  630016u

__global__ __launch_bounds__(256) void prep_hist_kernel(const float* __restrict__ q,
                                                        unsigned char* ws) {
  unsigned* counts  = (unsigned*)(ws + OFF_COUNTS);
  unsigned* cid_arr = (unsigned*)(ws + OFF_CID);
  const int i = blockIdx.x * 256 + threadIdx.x;   // 16384 threads
  const float x = q[3 * i + 0], y = q[3 * i + 1], z = q[3 * i + 2];
  int cx = (int)floorf((x - ORIGIN) * INV_CELL); cx = min(max(cx, 0), G - 1);
  int cy = (int)floorf((y - ORIGIN) * INV_CELL); cy = min(max(cy, 0), G - 1);
  int cz = (int)floorf((z - ORIGIN) * INV_CELL); cz = min(max(cz, 0), G - 1);
  const unsigned cid = (unsigned)((cx * G + cy) * G + cz);
  cid_arr[i] = cid;
  atomicAdd(counts + cid, 1u);
}

// Single block: prefix-sum counts -> starts; zero cursors; emit worklist of
// (group start, cell<<4 | cnt) entries with cnt <= 8; write entry count.
__global__ __launch_bounds__(1024) void prep_scan_kernel(unsigned char* ws) {
  unsigned* counts  = (unsigned*)(ws + OFF_COUNTS);
  unsigned* starts  = (unsigned*)(ws + OFF_STARTS);
  unsigned* cursors = (unsigned*)(ws + OFF_CURSORS);
  unsigned* wlcnt   = (unsigned*)(ws + OFF_WLCNT);
  int2*     wl      = (int2*)(ws + OFF_WL);

  __shared__ unsigned scnt[1024], sent[1024];
  const int t = threadIdx.x;
  unsigned c8[8];
  unsigned mycnt = 0, myent = 0;
#pragma unroll
  for (int i = 0; i < 8; ++i) {
    c8[i] = counts[t * 8 + i];
    mycnt += c8[i];
    myent += (c8[i] + 7u) >> 3;
  }
  scnt[t] = mycnt; sent[t] = myent;
  __syncthreads();
  for (int off = 1; off < 1024; off <<= 1) {
    unsigned a = 0, b = 0;
    if (t >= off) { a = scnt[t - off]; b = sent[t - off]; }
    __syncthreads();
    scnt[t] += a; sent[t] += b;
    __syncthreads();
  }
  unsigned run  = scnt[t] - mycnt;   // exclusive prefixes
  unsigned erun = sent[t] - myent;
#pragma unroll
  for (int i = 0; i < 8; ++i) {
    const int c = t * 8 + i;
    starts[c]  = run;
    cursors[c] = 0u;
    const unsigned n  = c8[i];
    const unsigned ne = (n + 7u) >> 3;
    for (unsigned g = 0; g < ne; ++g) {
      const unsigned rem = n - 8u * g;
      const unsigned cnt = rem < 8u ? rem : 8u;
      wl[erun + g] = make_int2((int)(run + 8u * g), (c << 4) | (int)cnt);
    }
    erun += ne;
    run  += n;
  }
  if (t == 1023) *wlcnt = sent[1023];
}

__global__ __launch_bounds__(256) void prep_scatter_kernel(const float* __restrict__ q,
                                                           unsigned char* ws) {
  const unsigned* starts  = (const unsigned*)(ws + OFF_STARTS);
  unsigned*       cursors = (unsigned*)(ws + OFF_CURSORS);
  const unsigned* cid_arr = (const unsigned*)(ws + OFF_CID);
  float4*         pts     = (float4*)(ws + OFF_PTS);
  const int i = blockIdx.x * 256 + threadIdx.x;   // 16384 threads
  const unsigned cid = cid_arr[i];
  const unsigned pos = starts[cid] + atomicAdd(cursors + cid, 1u);
  pts[pos] = make_float4(q[3 * i + 0], q[3 * i + 1], q[3 * i + 2], 0.0f);
}

// One wave per worklist entry (<=8 queries of one cell).
// Phase 1: scan 27-cell neighborhood (9 contiguous z-column ranges, bounds
//          prefetched); each LANE keeps a private sorted top-5 per query
//          (branchless med-shift, no wave serialization).
// Phase 2: exact top-8 per query via 8 rounds of wave extract-min over the
//          64x5 pool; sentinel 0.25 entries contribute exactly 0.
// Output: part[e] per entry -> bitwise-deterministic final sum.
__global__ __launch_bounds__(KNN_BLOCK) void knn_cells_kernel(unsigned char* ws) {
  const unsigned* starts = (const unsigned*)(ws + OFF_STARTS);
  const int2*     wl     = (const int2*)(ws + OFF_WL);
  const float4*   pts    = (const float4*)(ws + OFF_PTS);
  float*          part   = (float*)(ws + OFF_PART);
  const int wlc = (int)*(const unsigned*)(ws + OFF_WLCNT);

  const int lane = threadIdx.x & 63;
  const int gw   = blockIdx.x * (KNN_BLOCK / 64) + (threadIdx.x >> 6);

  // column visit order {dx,dy}: own first, then faces, then corners (2-bit codes)
  const unsigned DXC = 10569u;  // {0,1,-1,0,0,1,1,-1,-1}
  const unsigned DYC = 34965u;  // {0,0,0,1,-1,1,-1,1,-1}

  for (int e = gw; e < wlc; e += KNN_WAVES) {
    const int2 ent   = wl[e];
    const int qstart = ent.x;
    const int cell   = ent.y >> 4;
    const int cnt    = ent.y & 15;

    float qx[QPW], qy[QPW], qz[QPW];
#pragma unroll
    for (int k = 0; k < QPW; ++k) {
      if (k < cnt) {
        const float4 Q = pts[qstart + k];
        qx[k] = Q.x; qy[k] = Q.y; qz[k] = Q.z;
      } else {  // dummy query far away: never passes threshold
        qx[k] = 1.0e4f; qy[k] = 1.0e4f; qz[k] = 1.0e4f;
      }
    }

    // Private per-lane sorted top-5 per query (ascending). Global top-8 of a
    // query is in the union of lane top-5s unless one lane sees >=6 of the
    // top-8 (P ~ 3e-8/query; impact ~1e-7 vs 5e-2 tolerance).
    float P[QPW][5];
#pragma unroll
    for (int k = 0; k < QPW; ++k)
#pragma unroll
      for (int s = 0; s < 5; ++s) P[k][s] = D2MAX;

    const int cx  = cell / G2;
    const int rem = cell - cx * G2;
    const int cy  = rem / G;
    const int cz  = rem - cy * G;
    const int zlo = cz > 0 ? cz - 1 : 0;
    const int zhi = cz < G - 1 ? cz + 1 : G - 1;

    // Prefetch all 9 column range bounds (independent loads, one latency wall)
    int rs[9], re[9];
#pragma unroll
    for (int r = 0; r < 9; ++r) {
      const int dx = (int)((DXC >> (2 * r)) & 3u) - 1;
      const int dy = (int)((DYC >> (2 * r)) & 3u) - 1;
      const int nx = cx + dx, ny = cy + dy;
      if ((unsigned)nx < (unsigned)G && (unsigned)ny < (unsigned)G) {
        const int colbase = (nx * G + ny) * G;
        rs[r] = (int)starts[colbase + zlo];
        re[r] = (int)starts[colbase + zhi + 1];
      } else {
        rs[r] = 0; re[r] = 0;
      }
    }

#pragma unroll
    for (int r = 0; r < 9; ++r) {
      for (int j = rs[r]; j < re[r]; j += 64) {
        int idx = j + lane;
        const bool val = idx < re[r];
        if (!val) idx = re[r] - 1;
        const float4 Pt = pts[idx];
        float d2[QPW];
#pragma unroll
        for (int k = 0; k < QPW; ++k) {
          const float ddx = qx[k] - Pt.x;
          const float ddy = qy[k] - Pt.y;
          const float ddz = qz[k] - Pt.z;
          float dd = fmaf(ddz, ddz, fmaf(ddy, ddy, ddx * ddx));
          d2[k] = val ? dd : 1.0e9f;   // self -> exactly 0, excluded below
        }
#pragma unroll
        for (int k = 0; k < QPW; ++k) {
          const float v = d2[k];
          if (v < P[k][4] && v != 0.0f) {   // lane-parallel masked insert
            P[k][4] = fmaxf(P[k][3], fminf(v, P[k][4]));
            P[k][3] = fmaxf(P[k][2], fminf(v, P[k][3]));
            P[k][2] = fmaxf(P[k][1], fminf(v, P[k][2]));
            P[k][1] = fmaxf(P[k][0], fminf(v, P[k][1]));
            P[k][0] = fminf(P[k][0], v);
          }
        }
      }
    }

    // Phase 2: per query, extract the 8 smallest of the 64x5 pool.
    float accE = 0.0f;
#pragma unroll
    for (int k = 0; k < QPW; ++k) {
      if (k < cnt) {
        float a0 = P[k][0], a1 = P[k][1], a2 = P[k][2], a3 = P[k][3], a4 = P[k][4];
#pragma unroll
        for (int rr = 0; rr < 8; ++rr) {
          float m = a0;
          m = fminf(m, __shfl_xor(m, 1));
          m = fminf(m, __shfl_xor(m, 2));
          m = fminf(m, __shfl_xor(m, 4));
          m = fminf(m, __shfl_xor(m, 8));
          m = fminf(m, __shfl_xor(m, 16));
          m = fminf(m, __shfl_xor(m, 32));
          accE += 0.5f - sqrtf(m);   // m <= 0.25 always; sentinel -> +0
          const unsigned long long bal = __ballot(a0 == m);
          const int first = __ffsll(bal) - 1;
          const bool adv = (lane == first);
          a0 = adv ? a1 : a0;
          a1 = adv ? a2 : a1;
          a2 = adv ? a3 : a2;
          a3 = adv ? a4 : a3;
          a4 = adv ? D2MAX : a4;
        }
      }
    }

    if (lane == 0) part[e] = accE;   // every entry written exactly once
  }
}

__global__ __launch_bounds__(256) void final_reduce2_kernel(const unsigned char* ws,
                                                            float* __restrict__ out) {
  const float* part = (const float*)(ws + OFF_PART);
  const int wlc = (int)*(const unsigned*)(ws + OFF_WLCNT);
  const int tid = threadIdx.x;
  float v = 0.0f;
  for (int i = tid; i < wlc; i += 256) v += part[i];
#pragma unroll
  for (int off = 1; off < 64; off <<= 1) v += __shfl_xor(v, off);
  __shared__ float r[4];
  if ((tid & 63) == 0) r[tid >> 6] = v;
  __syncthreads();
  if (tid == 0) out[0] = (r[0] + r[1] + r[2] + r[3]) * (1.0f / (float)NPTS);
}

// ---------------- v2 fallback (proven) if ws is too small ----------------
#define FB_TILE 2048
__global__ __launch_bounds__(512) void knn_loss_kernel(
    const float* __restrict__ q, float* __restrict__ block_sum) {
  __shared__ float4 tile[FB_TILE];
  __shared__ float  wsum[8];
  const int tid = threadIdx.x, lane = tid & 63, wave = tid >> 6;
  const int qbase = blockIdx.x * 32 + wave * 4;
  float qx[4], qy[4], qz[4], qq[4];
#pragma unroll
  for (int k = 0; k < 4; ++k) {
    const float x = q[3 * (qbase + k) + 0];
    const float y = q[3 * (qbase + k) + 1];
    const float z = q[3 * (qbase + k) + 2];
    qx[k] = x; qy[k] = y; qz[k] = z;
    qq[k] = fmaf(z, z, fmaf(y, y, x * x));
  }
  float L[4][8];
#pragma unroll
  for (int k = 0; k < 4; ++k)
#pragma unroll
    for (int s = 0; s < 8; ++s) L[k][s] = D2MAX;
  for (int t = 0; t < NPTS / FB_TILE; ++t) {
    const int tb = t * FB_TILE;
#pragma unroll
    for (int s2 = 0; s2 < FB_TILE / 512; ++s2) {
      const int p = s2 * 512 + tid, gp = tb + p;
      const float x = q[3 * gp], y = q[3 * gp + 1], z = q[3 * gp + 2];
      tile[p] = make_float4(x, y, z, fmaf(z, z, fmaf(y, y, x * x)));
    }
    __syncthreads();
#pragma unroll 2
    for (int s = 0; s < FB_TILE / 64; ++s) {
      const float4 p = tile[s * 64 + lane];
      float d2[4];
#pragma unroll
      for (int k = 0; k < 4; ++k) {
        const float dt = fmaf(qx[k], p.x, fmaf(qy[k], p.y, qz[k] * p.z));
        d2[k] = fmaf(-2.0f, dt, qq[k] + p.w);
      }
      unsigned long long m[4];
#pragma unroll
      for (int k = 0; k < 4; ++k) m[k] = __ballot(d2[k] < L[k][7]);
      if (m[0] | m[1] | m[2] | m[3]) {
        const int jb = tb + s * 64;
#pragma unroll
        for (int k = 0; k < 4; ++k) {
          unsigned long long mk = m[k];
          while (mk) {
            const int i = __ffsll(mk) - 1;
            mk &= mk - 1;
            const float v = __shfl(d2[k], i);
            if ((jb + i) != (qbase + k) && v < L[k][7]) {
              L[k][7] = fmaxf(L[k][6], fminf(v, L[k][7]));
              L[k][6] = fmaxf(L[k][5], fminf(v, L[k][6]));
              L[k][5] = fmaxf(L[k][4], fminf(v, L[k][5]));
              L[k][4] = fmaxf(L[k][3], fminf(v, L[k][4]));
              L[k][3] = fmaxf(L[k][2], fminf(v, L[k][3]));
              L[k][2] = fmaxf(L[k][1], fminf(v, L[k][2]));
              L[k][1] = fmaxf(L[k][0], fminf(v, L[k][1]));
              L[k][0] = fminf(L[k][0], v);
            }
          }
        }
      }
    }
    __syncthreads();
  }
  float acc = 0.0f;
#pragma unroll
  for (int k = 0; k < 4; ++k)
#pragma unroll
    for (int s = 0; s < 8; ++s) acc += 0.5f - sqrtf(fmaxf(L[k][s], 0.0f));
  if (lane == 0) wsum[wave] = acc;
  __syncthreads();
  if (tid == 0) {
    float s = 0.0f;
#pragma unroll
    for (int w = 0; w < 8; ++w) s += wsum[w];
    block_sum[blockIdx.x] = s;
  }
}

__global__ __launch_bounds__(256) void final_reduce_kernel(
    const float* __restrict__ bs, float* __restrict__ out) {
  const int tid = threadIdx.x;
  float v = bs[tid] + bs[tid + 256];
#pragma unroll
  for (int off = 1; off < 64; off <<= 1) v += __shfl_xor(v, off);
  __shared__ float r[4];
  if ((tid & 63) == 0) r[tid >> 6] = v;
  __syncthreads();
  if (tid == 0) out[0] = (r[0] + r[1] + r[2] + r[3]) * (1.0f / (float)NPTS);
}

extern "C" void kernel_launch(void* const* d_in, const int* in_sizes, int n_in,
                              void* d_out, int out_size, void* d_ws, size_t ws_size,
                              hipStream_t stream) {
  const float* q = (const float*)d_in[0];
  unsigned char* ws = (unsigned char*)d_ws;
  if (ws_size >= WS_REQUIRED) {
    hipMemsetAsync(ws + OFF_COUNTS, 0, 32768, stream);   // counts only
    prep_hist_kernel<<<64, 256, 0, stream>>>(q, ws);
    prep_scan_kernel<<<1, 1024, 0, stream>>>(ws);
    prep_scatter_kernel<<<64, 256, 0, stream>>>(q, ws);
    knn_cells_kernel<<<KNN_GRID, KNN_BLOCK, 0, stream>>>(ws);
    final_reduce2_kernel<<<1, 256, 0, stream>>>(ws, (float*)d_out);
  } else {
    float* block_sum = (float*)d_ws;
    knn_loss_kernel<<<512, 512, 0, stream>>>(q, block_sum);
    final_reduce_kernel<<<1, 256, 0, stream>>>(block_sum, (float*)d_out);
  }
}